// Round 3
// baseline (123.235 us; speedup 1.0000x reference)
//
#include <hip/hip_runtime.h>

// Real solid spherical harmonics up to l=6 (49 outputs) for N points.
// v3: same as v2 but nontemporal stores use a clang ext_vector_type float4
// (the builtin rejects HIP_vector_type).

namespace {

constexpr int MAXL   = 6;
constexpr int NOUT   = (MAXL + 1) * (MAXL + 1);  // 49
constexpr int NT_MAX = 256;

typedef float f4 __attribute__((ext_vector_type(4)));

struct Tab {
    int   dst[NT_MAX];
    int   px[NT_MAX];
    int   py[NT_MAX];
    int   pz[NT_MAX];
    float clm[NT_MAX];
    bool  last[NT_MAX];  // true on the final term of each (l,m) group
    int   cnt;
};

constexpr long long comb(int n, int k) {
    if (k < 0 || k > n) return 0;
    long long r = 1;
    for (int i = 0; i < k; ++i) r = r * (n - i) / (i + 1);  // exact at each step
    return r;
}

constexpr Tab build_tab() {
    Tab tb{};
    int k = 0;
    for (int l = 0; l <= MAXL; ++l) {
        for (int m = -l; m <= l; ++m) {
            const int am  = (m < 0) ? -m : m;
            const int v2s = (m < 0) ? 1 : 0;
            const int v2e = 2 * ((m < 0) ? (am - 1) / 2 : am / 2) + v2s;
            for (int t = 0; t <= (l - am) / 2; ++t) {
                for (int u = 0; u <= t; ++u) {
                    for (int v2 = v2s; v2 <= v2e; v2 += 2) {
                        const int parity = (t + (v2 - v2s) / 2) % 2;
                        double c = parity ? -1.0 : 1.0;
                        for (int i = 0; i < t; ++i) c *= 0.25;
                        c *= (double)comb(l, t);
                        c *= (double)((am + t <= l - t) ? comb(l - t, am + t) : 0);
                        c *= (double)comb(t, u);
                        c *= (double)((v2 <= am) ? comb(am, v2) : 0);
                        tb.dst[k] = l * (l + 1) + m;
                        tb.px[k]  = 2 * t + am - 2 * u - v2;
                        tb.py[k]  = 2 * u + v2;
                        tb.pz[k]  = l - 2 * t - am;
                        tb.clm[k] = (float)c;
                        tb.last[k] = false;
                        ++k;
                    }
                }
            }
            tb.last[k - 1] = true;  // every (l,m) has >=1 term
        }
    }
    tb.cnt = k;
    return tb;
}

constexpr Tab TB = build_tab();
static_assert(TB.cnt == 188, "expected 188 terms for max_l=6");

constexpr int BLOCK = 256;
constexpr int HALF  = 128;                 // points staged per phase
constexpr int SLAB4 = HALF * NOUT / 4;     // 1568 float4 per phase

}  // namespace

__global__ __launch_bounds__(BLOCK) void rsh_kernel(const float* __restrict__ xyz,
                                                    const float* __restrict__ ns,
                                                    float* __restrict__ out,
                                                    int N) {
    __shared__ float sm[HALF * NOUT];  // 25088 B -> 6 blocks/CU by LDS

    const int tid = threadIdx.x;
    const int blk = blockIdx.x;

    // ---- cooperative, coalesced float4 load of this block's xyz slab ----
    {
        const int nf = N * 3;  // 1.5M, fits int
        const int g0 = blk * (BLOCK * 3 / 4);  // blk*192, float4 index
        if (tid < BLOCK * 3 / 4) {
            const f4* x4 = (const f4*)xyz;
            f4 v = (f4){0.f, 0.f, 0.f, 0.f};
            const int g = g0 + tid;
            if (g * 4 + 3 < nf) {
                v = x4[g];
            } else {
#pragma unroll
                for (int t = 0; t < 4; ++t) {
                    const int f = g * 4 + t;
                    if (f < nf) v[t] = xyz[f];
                }
            }
            ((f4*)sm)[tid] = v;
        }
    }
    __syncthreads();

    const float x = sm[tid * 3 + 0];
    const float y = sm[tid * 3 + 1];
    const float z = sm[tid * 3 + 2];
    __syncthreads();  // everyone has read xyz before sm is overwritten

    const int lim4 = (N * NOUT) >> 2;   // 6.125M, fits int
    const int remF = (N * NOUT) & 3;

    // compute one point, streaming each finished (l,m) output to LDS row r.
    auto compute_and_stage = [&](int r) {
        float xp[MAXL + 1], yp[MAXL + 1], zp[MAXL + 1];
        xp[0] = yp[0] = zp[0] = 1.f;
#pragma unroll
        for (int p = 1; p <= MAXL; ++p) {
            xp[p] = xp[p - 1] * x;
            yp[p] = yp[p - 1] * y;
            zp[p] = zp[p - 1] * z;
        }
        float acc = 0.f;
#pragma unroll
        for (int k = 0; k < TB.cnt; ++k) {
            acc = fmaf(TB.clm[k], xp[TB.px[k]] * yp[TB.py[k]] * zp[TB.pz[k]], acc);
            if (TB.last[k]) {  // compile-time constant after unroll
                sm[r * NOUT + TB.dst[k]] = acc * ns[TB.dst[k]];
                acc = 0.f;
            }
        }
    };

    // cooperative nontemporal store of one 128-point slab
    auto store_slab = [&](int phase) {
        const f4* s4 = (const f4*)sm;
        f4* o4 = (f4*)out;
        const int base4 = blk * (BLOCK * NOUT / 4) + phase * SLAB4;
#pragma unroll
        for (int it = 0; it < (SLAB4 + BLOCK - 1) / BLOCK; ++it) {  // 7 iters
            const int f = it * BLOCK + tid;
            if (f < SLAB4) {
                const int g = base4 + f;
                if (g < lim4) {
                    __builtin_nontemporal_store(s4[f], o4 + g);
                } else if (g == lim4 && remF) {
                    // final partial float4 (only if N*49 % 4 != 0)
#pragma unroll
                    for (int t = 0; t < 3; ++t)
                        if (t < remF) out[g * 4 + t] = sm[f * 4 + t];
                }
            }
        }
    };

    if (tid < HALF) compute_and_stage(tid);
    __syncthreads();
    store_slab(0);
    __syncthreads();
    if (tid >= HALF) compute_and_stage(tid - HALF);
    __syncthreads();
    store_slab(1);
}

extern "C" void kernel_launch(void* const* d_in, const int* in_sizes, int n_in,
                              void* d_out, int out_size, void* d_ws, size_t ws_size,
                              hipStream_t stream) {
    const float* xyz = (const float*)d_in[0];
    const float* ns  = (const float*)d_in[2];  // ns_lms [49]
    float* out = (float*)d_out;

    const int N = in_sizes[0] / 3;
    const int grid = (N + BLOCK - 1) / BLOCK;
    rsh_kernel<<<grid, BLOCK, 0, stream>>>(xyz, ns, out, N);
}